// Round 1
// 569.278 us; speedup vs baseline: 1.2238x; 1.2238x over previous
//
#include <hip/hip_runtime.h>
#include <cstdint>
#include <cstddef>

#define MR 2048
#define NC 4096
#define M3 683
#define SEG 64        // segments for 2048-row cumsums
#define HSEG 32       // MR/SEG
#define SEGD 22       // segments for 683-row cumsum
#define H3D 32        // rows per decay segment (ceil(683/22)=32)
#define VT 64         // vertical box tile height
#define VTILES 32     // MR/VT
#define NORM (1.0f/9604.0f)
// skewed LDS index: +1 float pad per 16 → stride-17 between threads, no bank collisions
#define SK(k) ((k)+((k)>>4))

__device__ __forceinline__ float sp(float v){
  // jax.nn.softplus = max(x,0) + log1p(exp(-|x|))
  return fmaxf(v, 0.0f) + log1pf(expf(-fabsf(v)));
}

// ---- segmented column scans (two-pass), caching the elementwise product ----

__global__ void seg_sum_decay(const float* __restrict__ bneg, const float* __restrict__ dcol,
                              float* __restrict__ TD, float* __restrict__ Pd){
  int s = blockIdx.x;
  int j = blockIdx.y*blockDim.x + threadIdx.x;
  int i0 = s*H3D, i1 = min(M3, i0+H3D);
  float acc = 0.f;
  int i = i0;
  for(; i+8<=i1; i+=8){
    float bv[8], dv[8];
    #pragma unroll
    for(int t=0;t<8;t++){ bv[t]=bneg[(i+t)*NC+j]; dv[t]=dcol[(i+t)*NC+j]; }
    #pragma unroll
    for(int t=0;t<8;t++){ float x=bv[t]*sp(dv[t]); TD[(i+t)*NC+j]=x; acc+=x; }
  }
  for(; i<i1; i++){ float x=bneg[i*NC+j]*sp(dcol[i*NC+j]); TD[i*NC+j]=x; acc+=x; }
  Pd[s*NC+j] = acc;
}

__global__ void seg_sum_b(const float* __restrict__ b, const float* __restrict__ w,
                          float* __restrict__ TB, float* __restrict__ Pb){
  int s = blockIdx.x;
  int j = blockIdx.y*blockDim.x + threadIdx.x;
  int i0 = s*HSEG;
  float acc=0.f;
  for(int g=0;g<HSEG;g+=8){
    float bv[8], wv[8];
    #pragma unroll
    for(int t=0;t<8;t++){ int i=i0+g+t; bv[t]=b[i*NC+j]; wv[t]=w[i*NC+j]; }
    #pragma unroll
    for(int t=0;t<8;t++){ int i=i0+g+t; float x=bv[t]*sp(wv[t]); TB[i*NC+j]=x; acc+=x; }
  }
  Pb[s*NC+j]=acc;
}

template<int SEGS>
__global__ void scan_excl_t(float* __restrict__ P){
  int j = blockIdx.x*blockDim.x + threadIdx.x;
  float run=0.f;
  int s=0;
  for(; s+8<=SEGS; s+=8){
    float v[8];
    #pragma unroll
    for(int t=0;t<8;t++) v[t]=P[(s+t)*NC+j];
    #pragma unroll
    for(int t=0;t<8;t++){ P[(s+t)*NC+j]=run; run+=v[t]; }
  }
  for(; s<SEGS; s++){ float t=P[s*NC+j]; P[s*NC+j]=run; run+=t; }
}

__global__ void decay_finalize(const float* __restrict__ TD,
                               const float* __restrict__ Pd, float* __restrict__ dc){
  int s=blockIdx.x;
  int j=blockIdx.y*blockDim.x+threadIdx.x;
  int i0=s*H3D, i1=min(M3,i0+H3D);
  float run = Pd[s*NC+j];
  int i=i0;
  for(; i+8<=i1; i+=8){
    float tv[8];
    #pragma unroll
    for(int t=0;t<8;t++) tv[t]=TD[(i+t)*NC+j];
    #pragma unroll
    for(int t=0;t<8;t++){ run+=tv[t]; dc[(i+t)*NC+j]=run; }
  }
  for(; i<i1; i++){ run += TD[i*NC+j]; dc[i*NC+j]=run; }
}

// ---- phase 1: b cumsum + decay upsample + b_adpt + x ----
__global__ void phase1(const float* __restrict__ TB,
                       const float* __restrict__ Pb, const float* __restrict__ dc,
                       const float* __restrict__ fg, const float* __restrict__ fm,
                       const float* __restrict__ bold, const float* __restrict__ hX,
                       const float* __restrict__ recon,
                       float* __restrict__ out0, float* __restrict__ out3,
                       float* __restrict__ X){
  int s=blockIdx.x;
  int j=blockIdx.y*blockDim.x+threadIdx.x;
  int i0=s*HSEG;
  float run = Pb[s*NC+j];
  #pragma unroll 4
  for(int rr=0;rr<HSEG;rr++){
    int i=i0+rr;
    run += TB[i*NC+j];
    // jax.image.resize 'linear', half-pixel centers, edge weights renormalize == clamp
    float c = (i+0.5f)*(683.0f/2048.0f)-0.5f;
    float fl = floorf(c);
    float f = c-fl;
    int a0=(int)fl, a1=a0+1;
    a0 = a0<0?0:(a0>M3-1?M3-1:a0);
    a1 = a1<0?0:(a1>M3-1?M3-1:a1);
    float d = (1.f-f)*dc[a0*NC+j] + f*dc[a1*NC+j];
    float bf = run + d*(1.f - fg[i*NC+j]);
    out3[i*NC+j]=bf;
    float fmv = fm[i*NC+j];
    float ba = bf*fmv + bold[i*NC+j]*(1.f-fmv);
    out0[i*NC+j]=ba;
    X[i*NC+j] = hX[(4*i)*NC+j] + ba - recon[i*NC+j];
  }
}

// ---- horizontal 98-window sums via in-LDS row prefix (replicate-pad aware) ----
// wave-shfl scan (2 barriers instead of 16) + skewed LDS prefix arrays.

__global__ __launch_bounds__(256) void hbox_sq(const float* __restrict__ X,
                         float* __restrict__ H1, float* __restrict__ H2){
  __shared__ float C1[SK(NC)+1];
  __shared__ float C2[SK(NC)+1];
  __shared__ float w1[4];
  __shared__ float w2[4];
  int row=blockIdx.x, tid=threadIdx.x;
  int lane = tid & 63, wvid = tid >> 6;
  const float* xr = X + (size_t)row*NC;
  float v1[16], v2[16];
  int base=tid*16;
  float run1=0.f,run2=0.f;
  const float4* p4 = reinterpret_cast<const float4*>(xr+base);
  #pragma unroll
  for(int q=0;q<4;q++){
    float4 fq=p4[q];
    float e[4]={fq.x,fq.y,fq.z,fq.w};
    #pragma unroll
    for(int t=0;t<4;t++){
      run1+=e[t];      v1[q*4+t]=run1;
      run2+=e[t]*e[t]; v2[q*4+t]=run2;
    }
  }
  // wave-level inclusive scan of per-thread totals
  float s1=run1, s2=run2;
  #pragma unroll
  for(int off=1;off<64;off<<=1){
    float o1=__shfl_up(s1,off);
    float o2=__shfl_up(s2,off);
    if(lane>=off){ s1+=o1; s2+=o2; }
  }
  if(lane==63){ w1[wvid]=s1; w2[wvid]=s2; }
  __syncthreads();
  float b1=0.f,b2=0.f;
  #pragma unroll
  for(int q=0;q<4;q++) if(q<wvid){ b1+=w1[q]; b2+=w2[q]; }
  float ex1 = b1 + s1 - run1, ex2 = b2 + s2 - run2;
  if(tid==0){C1[SK(0)]=0.f;C2[SK(0)]=0.f;}
  #pragma unroll
  for(int e=0;e<16;e++){ int k=base+1+e; C1[SK(k)]=ex1+v1[e]; C2[SK(k)]=ex2+v2[e]; }
  __syncthreads();
  float first1=C1[SK(1)],  last1=C1[SK(NC)]-C1[SK(NC-1)];
  float first2=C2[SK(1)],  last2=C2[SK(NC)]-C2[SK(NC-1)];
  float* h1 = H1+(size_t)row*NC;
  float* h2 = H2+(size_t)row*NC;
  #pragma unroll
  for(int k=0;k<16;k++){
    int j=k*256+tid;
    int lo=j-48, hi=j+49;
    int li = lo<0?0:lo;
    int hc = hi>NC-1?NC-1:hi;
    float s1w=C1[SK(hc+1)]-C1[SK(li)];
    float s2w=C2[SK(hc+1)]-C2[SK(li)];
    if(lo<0){ s1w+=(float)(-lo)*first1; s2w+=(float)(-lo)*first2; }
    if(hi>NC-1){ s1w+=(float)(hi-(NC-1))*last1; s2w+=(float)(hi-(NC-1))*last2; }
    h1[j]=s1w; h2[j]=s2w;
  }
}

__global__ __launch_bounds__(256) void hbox_two(const float* __restrict__ A,
                         const float* __restrict__ B,
                         float* __restrict__ H1, float* __restrict__ H2){
  __shared__ float C1[SK(NC)+1];
  __shared__ float C2[SK(NC)+1];
  __shared__ float w1[4];
  __shared__ float w2[4];
  int row=blockIdx.x, tid=threadIdx.x;
  int lane = tid & 63, wvid = tid >> 6;
  const float* ar = A + (size_t)row*NC;
  const float* br = B + (size_t)row*NC;
  float v1[16], v2[16];
  int base=tid*16;
  float run1=0.f,run2=0.f;
  const float4* pa = reinterpret_cast<const float4*>(ar+base);
  const float4* pb = reinterpret_cast<const float4*>(br+base);
  #pragma unroll
  for(int q=0;q<4;q++){
    float4 fa=pa[q]; float4 fb=pb[q];
    float ea[4]={fa.x,fa.y,fa.z,fa.w};
    float eb[4]={fb.x,fb.y,fb.z,fb.w};
    #pragma unroll
    for(int t=0;t<4;t++){
      run1+=ea[t]; v1[q*4+t]=run1;
      run2+=eb[t]; v2[q*4+t]=run2;
    }
  }
  float s1=run1, s2=run2;
  #pragma unroll
  for(int off=1;off<64;off<<=1){
    float o1=__shfl_up(s1,off);
    float o2=__shfl_up(s2,off);
    if(lane>=off){ s1+=o1; s2+=o2; }
  }
  if(lane==63){ w1[wvid]=s1; w2[wvid]=s2; }
  __syncthreads();
  float b1=0.f,b2=0.f;
  #pragma unroll
  for(int q=0;q<4;q++) if(q<wvid){ b1+=w1[q]; b2+=w2[q]; }
  float ex1 = b1 + s1 - run1, ex2 = b2 + s2 - run2;
  if(tid==0){C1[SK(0)]=0.f;C2[SK(0)]=0.f;}
  #pragma unroll
  for(int e=0;e<16;e++){ int k=base+1+e; C1[SK(k)]=ex1+v1[e]; C2[SK(k)]=ex2+v2[e]; }
  __syncthreads();
  float first1=C1[SK(1)], last1=C1[SK(NC)]-C1[SK(NC-1)];
  float first2=C2[SK(1)], last2=C2[SK(NC)]-C2[SK(NC-1)];
  float* h1 = H1+(size_t)row*NC;
  float* h2 = H2+(size_t)row*NC;
  #pragma unroll
  for(int k=0;k<16;k++){
    int j=k*256+tid;
    int lo=j-48, hi=j+49;
    int li = lo<0?0:lo;
    int hc = hi>NC-1?NC-1:hi;
    float s1w=C1[SK(hc+1)]-C1[SK(li)];
    float s2w=C2[SK(hc+1)]-C2[SK(li)];
    if(lo<0){ s1w+=(float)(-lo)*first1; s2w+=(float)(-lo)*first2; }
    if(hi>NC-1){ s1w+=(float)(hi-(NC-1))*last1; s2w+=(float)(hi-(NC-1))*last2; }
    h1[j]=s1w; h2[j]=s2w;
  }
}

// ---- vertical 98-window sliding sums (rows i-48..i+49 clamped) ----
// Batched loads: all of a group's independent loads are issued before the
// serial accumulate/compute sweep -> ~32-48 loads in flight per wave.

__global__ void vbox_stage1(const float* __restrict__ H1, const float* __restrict__ H2,
                            float* __restrict__ Aimg, float* __restrict__ BBimg){
  int tile = blockIdx.x;
  int j = blockIdx.y*blockDim.x + threadIdx.x;
  int i0 = tile*VT;
  int ip = i0-1;                 // init window at row i0-1, slide into each row
  float Sa=0.f, Sb=0.f;
  for(int g=0; g<98; g+=14){
    float a1[14], a2[14];
    #pragma unroll
    for(int t=0;t<14;t++){
      int c = ip-48+g+t;
      int cc = c<0?0:(c>MR-1?MR-1:c);
      a1[t]=H1[cc*NC+j]; a2[t]=H2[cc*NC+j];
    }
    #pragma unroll
    for(int t=0;t<14;t++){ Sa+=a1[t]; Sb+=a2[t]; }
  }
  for(int g=0; g<VT; g+=8){
    float hu1[8],hd1[8],hu2[8],hd2[8];
    #pragma unroll
    for(int t=0;t<8;t++){
      int i=i0+g+t;
      int up=i+49; up=up>MR-1?MR-1:up;
      int dn=i-49; dn=dn<0?0:dn;
      hu1[t]=H1[up*NC+j]; hd1[t]=H1[dn*NC+j];
      hu2[t]=H2[up*NC+j]; hd2[t]=H2[dn*NC+j];
    }
    #pragma unroll
    for(int t=0;t<8;t++){
      int i=i0+g+t;
      Sa += hu1[t]-hd1[t];
      Sb += hu2[t]-hd2[t];
      float mx = Sa*NORM, mx2 = Sb*NORM;
      float var = mx2 - mx*mx;
      float A = var/(var+1.0f);
      float bb = mx - A*mx;
      Aimg[i*NC+j]=A; BBimg[i*NC+j]=bb;
    }
  }
}

// ---- vbox stage2 fused with phase3's diff/clip/scale partial-sum ----
// S lands in out2 (diff_adpt slot) whose previous content (bb_img) is dead.
// Unified tile-0 handling: dpre = +3e38 forces S[row0] = clip(d0 - huge) = 0.

__global__ void vbox2_fused(const float* __restrict__ H1, const float* __restrict__ H2,
                            const float* __restrict__ X, const float* __restrict__ ww,
                            float* __restrict__ diff, float* __restrict__ S,
                            float* __restrict__ Pc){
  int tile = blockIdx.x;
  int j = blockIdx.y*blockDim.x + threadIdx.x;
  int i0 = tile*VT;
  int ip = i0-1;
  float Sa=0.f, Sb=0.f;
  for(int g=0; g<98; g+=14){
    float a1[14], a2[14];
    #pragma unroll
    for(int t=0;t<14;t++){
      int c = ip-48+g+t;
      int cc = c<0?0:(c>MR-1?MR-1:c);
      a1[t]=H1[cc*NC+j]; a2[t]=H2[cc*NC+j];
    }
    #pragma unroll
    for(int t=0;t<14;t++){ Sa+=a1[t]; Sb+=a2[t]; }
  }
  float dpre, acc=0.f;
  if(tile==0) dpre = 3.0e38f;    // first row: S must be 0 (diff - diff == 0, clipped)
  else        dpre = (Sa*NORM)*X[(size_t)ip*NC+j] + Sb*NORM;
  for(int g=0; g<VT; g+=8){
    float hu1[8],hd1[8],hu2[8],hd2[8],xv[8],wv[8];
    #pragma unroll
    for(int t=0;t<8;t++){
      int i=i0+g+t;
      int up=i+49; up=up>MR-1?MR-1:up;
      int dn=i-49; dn=dn<0?0:dn;
      hu1[t]=H1[up*NC+j]; hd1[t]=H1[dn*NC+j];
      hu2[t]=H2[up*NC+j]; hd2[t]=H2[dn*NC+j];
      xv[t]=X[(size_t)i*NC+j]; wv[t]=ww[i*NC+j];
    }
    #pragma unroll
    for(int t=0;t<8;t++){
      int i=i0+g+t;
      Sa += hu1[t]-hd1[t];
      Sb += hu2[t]-hd2[t];
      float d = (Sa*NORM)*xv[t] + Sb*NORM;
      diff[i*NC+j]=d;
      float v = d-dpre; v = v>0.f? v:0.f;
      float sv = v*sp(wv[t]);
      S[i*NC+j]=sv; acc+=sv; dpre=d;
    }
  }
  Pc[tile*NC+j]=acc;
}

// ---- phase 3 final: column cumsum of S (in out2, overwritten in place),
//      write diff_adpt, update b_adpt ----

__global__ void phase3_final(const float* __restrict__ Pc,
                             float* __restrict__ out0, float* __restrict__ out2){
  int s=blockIdx.x;
  int j=blockIdx.y*blockDim.x+threadIdx.x;
  int i0=s*VT;
  float run = Pc[s*NC+j];
  for(int g=0; g<VT; g+=8){
    float sv[8], o0[8];
    #pragma unroll
    for(int t=0;t<8;t++){ int i=i0+g+t; sv[t]=out2[i*NC+j]; o0[t]=out0[i*NC+j]; }
    #pragma unroll
    for(int t=0;t<8;t++){
      int i=i0+g+t;
      run += sv[t];
      out2[i*NC+j]=run;
      out0[i*NC+j]=o0[t]-run;
    }
  }
}

extern "C" void kernel_launch(void* const* d_in, const int* in_sizes, int n_in,
                              void* d_out, int out_size, void* d_ws, size_t ws_size,
                              hipStream_t stream){
  const float* b    = (const float*)d_in[0];
  const float* bneg = (const float*)d_in[1];
  const float* fg   = (const float*)d_in[2];
  const float* hX   = (const float*)d_in[3];
  const float* recon= (const float*)d_in[4];
  const float* fm   = (const float*)d_in[5];
  const float* bold = (const float*)d_in[6];
  // d_in[7] = r (int scalar, ==4) — shapes hardcoded
  const float* w    = (const float*)d_in[8];
  const float* dcol = (const float*)d_in[9];
  const float* ww   = (const float*)d_in[10];

  float* out  = (float*)d_out;
  float* out0 = out;                       // b_adpt
  float* out1 = out + (size_t)MR*NC;       // diff (A_img scratch mid-pipe)
  float* out2 = out + 2ull*MR*NC;          // diff_adpt (bb_img scratch, then S, then cumsum)
  float* out3 = out + 3ull*MR*NC;          // b

  float* wsf = (float*)d_ws;
  float* X  = wsf;                         // MR*NC
  float* H1 = wsf + 1ull*MR*NC;            // MR*NC   (TD early)
  float* H2 = wsf + 2ull*MR*NC;            // MR*NC   (TB early)
  float* DC = wsf + 3ull*MR*NC;            // M3*NC
  float* Pb = DC + (size_t)M3*NC;          // SEG*NC
  float* Pd = Pb + (size_t)SEG*NC;         // SEGD*NC
  float* Pc = Pd + (size_t)SEGD*NC;        // VTILES*NC
  float* TD = H1;                          // M3*NC  (dead before hbox_sq writes H1)
  float* TB = H2;                          // MR*NC  (dead before hbox_sq writes H2)

  seg_sum_decay<<<dim3(SEGD,NC/256),256,0,stream>>>(bneg,dcol,TD,Pd);
  seg_sum_b    <<<dim3(SEG, NC/256),256,0,stream>>>(b,w,TB,Pb);
  scan_excl_t<SEGD><<<NC/256,256,0,stream>>>(Pd);
  scan_excl_t<SEG> <<<NC/256,256,0,stream>>>(Pb);
  decay_finalize<<<dim3(SEGD,NC/256),256,0,stream>>>(TD,Pd,DC);
  phase1       <<<dim3(SEG, NC/256),256,0,stream>>>(TB,Pb,DC,fg,fm,bold,hX,recon,out0,out3,X);
  hbox_sq      <<<MR,256,0,stream>>>(X,H1,H2);
  vbox_stage1  <<<dim3(VTILES,NC/256),256,0,stream>>>(H1,H2,out1,out2);
  hbox_two     <<<MR,256,0,stream>>>(out1,out2,H1,H2);
  vbox2_fused  <<<dim3(VTILES,NC/256),256,0,stream>>>(H1,H2,X,ww,out1,out2,Pc);
  scan_excl_t<VTILES><<<NC/256,256,0,stream>>>(Pc);
  phase3_final <<<dim3(VTILES,NC/256),256,0,stream>>>(Pc,out0,out2);
}

// Round 2
// 569.187 us; speedup vs baseline: 1.2240x; 1.0002x over previous
//
#include <hip/hip_runtime.h>
#include <cstdint>
#include <cstddef>

#define MR 2048
#define NC 4096
#define M3 683
#define SEG 64        // segments for 2048-row cumsums
#define HSEG 32       // MR/SEG
#define SEGD 22       // segments for 683-row cumsum
#define H3D 32        // rows per decay segment (ceil(683/22)=32)
#define VT 64         // vertical box tile height
#define VTILES 32     // MR/VT
#define NORM (1.0f/9604.0f)
// skewed LDS index: +1 float pad per 16 → stride-17 between threads, no bank collisions
#define SK(k) ((k)+((k)>>4))

__device__ __forceinline__ float sp(float v){
  // jax.nn.softplus = max(x,0) + log1p(exp(-|x|))
  return fmaxf(v, 0.0f) + log1pf(expf(-fabsf(v)));
}

// ---- segmented column scans pass 1 (fused decay+b), caching the product ----

__global__ void seg_sum_both(const float* __restrict__ bneg, const float* __restrict__ dcol,
                             const float* __restrict__ b, const float* __restrict__ w,
                             float* __restrict__ TD, float* __restrict__ Pd,
                             float* __restrict__ TB, float* __restrict__ Pb){
  int s = blockIdx.x;
  int j = blockIdx.y*blockDim.x + threadIdx.x;
  if(s < SEGD){
    int i0 = s*H3D, i1 = min(M3, i0+H3D);
    float acc = 0.f;
    int i = i0;
    for(; i+8<=i1; i+=8){
      float bv[8], dv[8];
      #pragma unroll
      for(int t=0;t<8;t++){ bv[t]=bneg[(i+t)*NC+j]; dv[t]=dcol[(i+t)*NC+j]; }
      #pragma unroll
      for(int t=0;t<8;t++){ float x=bv[t]*sp(dv[t]); TD[(i+t)*NC+j]=x; acc+=x; }
    }
    for(; i<i1; i++){ float x=bneg[i*NC+j]*sp(dcol[i*NC+j]); TD[i*NC+j]=x; acc+=x; }
    Pd[s*NC+j] = acc;
  } else {
    int sb = s - SEGD;
    int i0 = sb*HSEG;
    float acc=0.f;
    for(int g=0;g<HSEG;g+=8){
      float bv[8], wv[8];
      #pragma unroll
      for(int t=0;t<8;t++){ int i=i0+g+t; bv[t]=b[i*NC+j]; wv[t]=w[i*NC+j]; }
      #pragma unroll
      for(int t=0;t<8;t++){ int i=i0+g+t; float x=bv[t]*sp(wv[t]); TB[i*NC+j]=x; acc+=x; }
    }
    Pb[sb*NC+j]=acc;
  }
}

// ---- pass 2: exclusive scans of both partial arrays in one launch ----

__global__ void scan_excl_both(float* __restrict__ Pd, float* __restrict__ Pb){
  int j = blockIdx.x*blockDim.x + threadIdx.x;
  {
    float run=0.f; int s=0;
    for(; s+8<=SEGD; s+=8){
      float v[8];
      #pragma unroll
      for(int t=0;t<8;t++) v[t]=Pd[(s+t)*NC+j];
      #pragma unroll
      for(int t=0;t<8;t++){ Pd[(s+t)*NC+j]=run; run+=v[t]; }
    }
    for(; s<SEGD; s++){ float t=Pd[s*NC+j]; Pd[s*NC+j]=run; run+=t; }
  }
  {
    float run=0.f;
    for(int s=0; s<SEG; s+=8){
      float v[8];
      #pragma unroll
      for(int t=0;t<8;t++) v[t]=Pb[(s+t)*NC+j];
      #pragma unroll
      for(int t=0;t<8;t++){ Pb[(s+t)*NC+j]=run; run+=v[t]; }
    }
  }
}

template<int SEGS>
__global__ void scan_excl_t(float* __restrict__ P){
  int j = blockIdx.x*blockDim.x + threadIdx.x;
  float run=0.f;
  int s=0;
  for(; s+8<=SEGS; s+=8){
    float v[8];
    #pragma unroll
    for(int t=0;t<8;t++) v[t]=P[(s+t)*NC+j];
    #pragma unroll
    for(int t=0;t<8;t++){ P[(s+t)*NC+j]=run; run+=v[t]; }
  }
  for(; s<SEGS; s++){ float t=P[s*NC+j]; P[s*NC+j]=run; run+=t; }
}

__global__ void decay_finalize(const float* __restrict__ TD,
                               const float* __restrict__ Pd, float* __restrict__ dc){
  int s=blockIdx.x;
  int j=blockIdx.y*blockDim.x+threadIdx.x;
  int i0=s*H3D, i1=min(M3,i0+H3D);
  float run = Pd[s*NC+j];
  int i=i0;
  for(; i+8<=i1; i+=8){
    float tv[8];
    #pragma unroll
    for(int t=0;t<8;t++) tv[t]=TD[(i+t)*NC+j];
    #pragma unroll
    for(int t=0;t<8;t++){ run+=tv[t]; dc[(i+t)*NC+j]=run; }
  }
  for(; i<i1; i++){ run += TD[i*NC+j]; dc[i*NC+j]=run; }
}

// ---- phase 1: b cumsum + decay upsample + b_adpt + x (batched loads) ----
__global__ void phase1(const float* __restrict__ TB,
                       const float* __restrict__ Pb, const float* __restrict__ dc,
                       const float* __restrict__ fg, const float* __restrict__ fm,
                       const float* __restrict__ bold, const float* __restrict__ hX,
                       const float* __restrict__ recon,
                       float* __restrict__ out0, float* __restrict__ out3,
                       float* __restrict__ X){
  int s=blockIdx.x;
  int j=blockIdx.y*blockDim.x+threadIdx.x;
  int i0=s*HSEG;
  float run = Pb[s*NC+j];
  for(int g=0; g<HSEG; g+=8){
    float tb[8], fgv[8], fmv[8], bo[8], hx[8], rc[8], d0[8], d1[8], fw[8];
    #pragma unroll
    for(int t=0;t<8;t++){
      int i=i0+g+t;
      tb[t]=TB[i*NC+j];
      fgv[t]=fg[i*NC+j];
      fmv[t]=fm[i*NC+j];
      bo[t]=bold[i*NC+j];
      hx[t]=hX[(size_t)(4*i)*NC+j];
      rc[t]=recon[i*NC+j];
      // jax.image.resize 'linear', half-pixel centers, edge clamp
      float c = (i+0.5f)*(683.0f/2048.0f)-0.5f;
      float fl = floorf(c);
      fw[t] = c-fl;
      int a0=(int)fl, a1=a0+1;
      a0 = a0<0?0:(a0>M3-1?M3-1:a0);
      a1 = a1<0?0:(a1>M3-1?M3-1:a1);
      d0[t]=dc[a0*NC+j]; d1[t]=dc[a1*NC+j];
    }
    #pragma unroll
    for(int t=0;t<8;t++){
      int i=i0+g+t;
      run += tb[t];
      float d = (1.f-fw[t])*d0[t] + fw[t]*d1[t];
      float bf = run + d*(1.f - fgv[t]);
      out3[i*NC+j]=bf;
      float ba = bf*fmv[t] + bo[t]*(1.f-fmv[t]);
      out0[i*NC+j]=ba;
      X[i*NC+j] = hx[t] + ba - rc[t];
    }
  }
}

// ---- horizontal 98-window sums via in-LDS row prefix (replicate-pad aware) ----
// wave-shfl scan (2 barriers) + skewed LDS prefix arrays.

__global__ __launch_bounds__(256) void hbox_sq(const float* __restrict__ X,
                         float* __restrict__ H1, float* __restrict__ H2){
  __shared__ float C1[SK(NC)+1];
  __shared__ float C2[SK(NC)+1];
  __shared__ float w1[4];
  __shared__ float w2[4];
  int row=blockIdx.x, tid=threadIdx.x;
  int lane = tid & 63, wvid = tid >> 6;
  const float* xr = X + (size_t)row*NC;
  float v1[16], v2[16];
  int base=tid*16;
  float run1=0.f,run2=0.f;
  const float4* p4 = reinterpret_cast<const float4*>(xr+base);
  #pragma unroll
  for(int q=0;q<4;q++){
    float4 fq=p4[q];
    float e[4]={fq.x,fq.y,fq.z,fq.w};
    #pragma unroll
    for(int t=0;t<4;t++){
      run1+=e[t];      v1[q*4+t]=run1;
      run2+=e[t]*e[t]; v2[q*4+t]=run2;
    }
  }
  // wave-level inclusive scan of per-thread totals
  float s1=run1, s2=run2;
  #pragma unroll
  for(int off=1;off<64;off<<=1){
    float o1=__shfl_up(s1,off);
    float o2=__shfl_up(s2,off);
    if(lane>=off){ s1+=o1; s2+=o2; }
  }
  if(lane==63){ w1[wvid]=s1; w2[wvid]=s2; }
  __syncthreads();
  float b1=0.f,b2=0.f;
  #pragma unroll
  for(int q=0;q<4;q++) if(q<wvid){ b1+=w1[q]; b2+=w2[q]; }
  float ex1 = b1 + s1 - run1, ex2 = b2 + s2 - run2;
  if(tid==0){C1[SK(0)]=0.f;C2[SK(0)]=0.f;}
  #pragma unroll
  for(int e=0;e<16;e++){ int k=base+1+e; C1[SK(k)]=ex1+v1[e]; C2[SK(k)]=ex2+v2[e]; }
  __syncthreads();
  float first1=C1[SK(1)],  last1=C1[SK(NC)]-C1[SK(NC-1)];
  float first2=C2[SK(1)],  last2=C2[SK(NC)]-C2[SK(NC-1)];
  float* h1 = H1+(size_t)row*NC;
  float* h2 = H2+(size_t)row*NC;
  #pragma unroll
  for(int k=0;k<16;k++){
    int j=k*256+tid;
    int lo=j-48, hi=j+49;
    int li = lo<0?0:lo;
    int hc = hi>NC-1?NC-1:hi;
    float s1w=C1[SK(hc+1)]-C1[SK(li)];
    float s2w=C2[SK(hc+1)]-C2[SK(li)];
    if(lo<0){ s1w+=(float)(-lo)*first1; s2w+=(float)(-lo)*first2; }
    if(hi>NC-1){ s1w+=(float)(hi-(NC-1))*last1; s2w+=(float)(hi-(NC-1))*last2; }
    h1[j]=s1w; h2[j]=s2w;
  }
}

__global__ __launch_bounds__(256) void hbox_two(const float* __restrict__ A,
                         const float* __restrict__ B,
                         float* __restrict__ H1, float* __restrict__ H2){
  __shared__ float C1[SK(NC)+1];
  __shared__ float C2[SK(NC)+1];
  __shared__ float w1[4];
  __shared__ float w2[4];
  int row=blockIdx.x, tid=threadIdx.x;
  int lane = tid & 63, wvid = tid >> 6;
  const float* ar = A + (size_t)row*NC;
  const float* br = B + (size_t)row*NC;
  float v1[16], v2[16];
  int base=tid*16;
  float run1=0.f,run2=0.f;
  const float4* pa = reinterpret_cast<const float4*>(ar+base);
  const float4* pb = reinterpret_cast<const float4*>(br+base);
  #pragma unroll
  for(int q=0;q<4;q++){
    float4 fa=pa[q]; float4 fb=pb[q];
    float ea[4]={fa.x,fa.y,fa.z,fa.w};
    float eb[4]={fb.x,fb.y,fb.z,fb.w};
    #pragma unroll
    for(int t=0;t<4;t++){
      run1+=ea[t]; v1[q*4+t]=run1;
      run2+=eb[t]; v2[q*4+t]=run2;
    }
  }
  float s1=run1, s2=run2;
  #pragma unroll
  for(int off=1;off<64;off<<=1){
    float o1=__shfl_up(s1,off);
    float o2=__shfl_up(s2,off);
    if(lane>=off){ s1+=o1; s2+=o2; }
  }
  if(lane==63){ w1[wvid]=s1; w2[wvid]=s2; }
  __syncthreads();
  float b1=0.f,b2=0.f;
  #pragma unroll
  for(int q=0;q<4;q++) if(q<wvid){ b1+=w1[q]; b2+=w2[q]; }
  float ex1 = b1 + s1 - run1, ex2 = b2 + s2 - run2;
  if(tid==0){C1[SK(0)]=0.f;C2[SK(0)]=0.f;}
  #pragma unroll
  for(int e=0;e<16;e++){ int k=base+1+e; C1[SK(k)]=ex1+v1[e]; C2[SK(k)]=ex2+v2[e]; }
  __syncthreads();
  float first1=C1[SK(1)], last1=C1[SK(NC)]-C1[SK(NC-1)];
  float first2=C2[SK(1)], last2=C2[SK(NC)]-C2[SK(NC-1)];
  float* h1 = H1+(size_t)row*NC;
  float* h2 = H2+(size_t)row*NC;
  #pragma unroll
  for(int k=0;k<16;k++){
    int j=k*256+tid;
    int lo=j-48, hi=j+49;
    int li = lo<0?0:lo;
    int hc = hi>NC-1?NC-1:hi;
    float s1w=C1[SK(hc+1)]-C1[SK(li)];
    float s2w=C2[SK(hc+1)]-C2[SK(li)];
    if(lo<0){ s1w+=(float)(-lo)*first1; s2w+=(float)(-lo)*first2; }
    if(hi>NC-1){ s1w+=(float)(hi-(NC-1))*last1; s2w+=(float)(hi-(NC-1))*last2; }
    h1[j]=s1w; h2[j]=s2w;
  }
}

// ---- vertical 98-window sliding sums (rows i-48..i+49 clamped), batched ----

__global__ void vbox_stage1(const float* __restrict__ H1, const float* __restrict__ H2,
                            float* __restrict__ Aimg, float* __restrict__ BBimg){
  int tile = blockIdx.x;
  int j = blockIdx.y*blockDim.x + threadIdx.x;
  int i0 = tile*VT;
  int ip = i0-1;                 // init window at row i0-1, slide into each row
  float Sa=0.f, Sb=0.f;
  for(int g=0; g<98; g+=14){
    float a1[14], a2[14];
    #pragma unroll
    for(int t=0;t<14;t++){
      int c = ip-48+g+t;
      int cc = c<0?0:(c>MR-1?MR-1:c);
      a1[t]=H1[cc*NC+j]; a2[t]=H2[cc*NC+j];
    }
    #pragma unroll
    for(int t=0;t<14;t++){ Sa+=a1[t]; Sb+=a2[t]; }
  }
  for(int g=0; g<VT; g+=8){
    float hu1[8],hd1[8],hu2[8],hd2[8];
    #pragma unroll
    for(int t=0;t<8;t++){
      int i=i0+g+t;
      int up=i+49; up=up>MR-1?MR-1:up;
      int dn=i-49; dn=dn<0?0:dn;
      hu1[t]=H1[up*NC+j]; hd1[t]=H1[dn*NC+j];
      hu2[t]=H2[up*NC+j]; hd2[t]=H2[dn*NC+j];
    }
    #pragma unroll
    for(int t=0;t<8;t++){
      int i=i0+g+t;
      Sa += hu1[t]-hd1[t];
      Sb += hu2[t]-hd2[t];
      float mx = Sa*NORM, mx2 = Sb*NORM;
      float var = mx2 - mx*mx;
      float A = var/(var+1.0f);
      float bb = mx - A*mx;
      Aimg[i*NC+j]=A; BBimg[i*NC+j]=bb;
    }
  }
}

// ---- vbox stage2 fused with phase3's diff/clip/scale partial-sum ----
// S lands in out2 (diff_adpt slot) whose previous content (bb_img) is dead.
// Unified tile-0 handling: dpre = +3e38 forces S[row0] = clip(d0 - huge) = 0.

__global__ void vbox2_fused(const float* __restrict__ H1, const float* __restrict__ H2,
                            const float* __restrict__ X, const float* __restrict__ ww,
                            float* __restrict__ diff, float* __restrict__ S,
                            float* __restrict__ Pc){
  int tile = blockIdx.x;
  int j = blockIdx.y*blockDim.x + threadIdx.x;
  int i0 = tile*VT;
  int ip = i0-1;
  float Sa=0.f, Sb=0.f;
  for(int g=0; g<98; g+=14){
    float a1[14], a2[14];
    #pragma unroll
    for(int t=0;t<14;t++){
      int c = ip-48+g+t;
      int cc = c<0?0:(c>MR-1?MR-1:c);
      a1[t]=H1[cc*NC+j]; a2[t]=H2[cc*NC+j];
    }
    #pragma unroll
    for(int t=0;t<14;t++){ Sa+=a1[t]; Sb+=a2[t]; }
  }
  float dpre, acc=0.f;
  if(tile==0) dpre = 3.0e38f;    // first row: S must be 0 (diff - diff == 0, clipped)
  else        dpre = (Sa*NORM)*X[(size_t)ip*NC+j] + Sb*NORM;
  for(int g=0; g<VT; g+=8){
    float hu1[8],hd1[8],hu2[8],hd2[8],xv[8],wv[8];
    #pragma unroll
    for(int t=0;t<8;t++){
      int i=i0+g+t;
      int up=i+49; up=up>MR-1?MR-1:up;
      int dn=i-49; dn=dn<0?0:dn;
      hu1[t]=H1[up*NC+j]; hd1[t]=H1[dn*NC+j];
      hu2[t]=H2[up*NC+j]; hd2[t]=H2[dn*NC+j];
      xv[t]=X[(size_t)i*NC+j]; wv[t]=ww[i*NC+j];
    }
    #pragma unroll
    for(int t=0;t<8;t++){
      int i=i0+g+t;
      Sa += hu1[t]-hd1[t];
      Sb += hu2[t]-hd2[t];
      float d = (Sa*NORM)*xv[t] + Sb*NORM;
      diff[i*NC+j]=d;
      float v = d-dpre; v = v>0.f? v:0.f;
      float sv = v*sp(wv[t]);
      S[i*NC+j]=sv; acc+=sv; dpre=d;
    }
  }
  Pc[tile*NC+j]=acc;
}

// ---- phase 3 final: column cumsum of S (in out2, overwritten in place),
//      write diff_adpt, update b_adpt ----

__global__ void phase3_final(const float* __restrict__ Pc,
                             float* __restrict__ out0, float* __restrict__ out2){
  int s=blockIdx.x;
  int j=blockIdx.y*blockDim.x+threadIdx.x;
  int i0=s*VT;
  float run = Pc[s*NC+j];
  for(int g=0; g<VT; g+=8){
    float sv[8], o0[8];
    #pragma unroll
    for(int t=0;t<8;t++){ int i=i0+g+t; sv[t]=out2[i*NC+j]; o0[t]=out0[i*NC+j]; }
    #pragma unroll
    for(int t=0;t<8;t++){
      int i=i0+g+t;
      run += sv[t];
      out2[i*NC+j]=run;
      out0[i*NC+j]=o0[t]-run;
    }
  }
}

extern "C" void kernel_launch(void* const* d_in, const int* in_sizes, int n_in,
                              void* d_out, int out_size, void* d_ws, size_t ws_size,
                              hipStream_t stream){
  const float* b    = (const float*)d_in[0];
  const float* bneg = (const float*)d_in[1];
  const float* fg   = (const float*)d_in[2];
  const float* hX   = (const float*)d_in[3];
  const float* recon= (const float*)d_in[4];
  const float* fm   = (const float*)d_in[5];
  const float* bold = (const float*)d_in[6];
  // d_in[7] = r (int scalar, ==4) — shapes hardcoded
  const float* w    = (const float*)d_in[8];
  const float* dcol = (const float*)d_in[9];
  const float* ww   = (const float*)d_in[10];

  float* out  = (float*)d_out;
  float* out0 = out;                       // b_adpt
  float* out1 = out + (size_t)MR*NC;       // diff (A_img scratch mid-pipe)
  float* out2 = out + 2ull*MR*NC;          // diff_adpt (bb_img scratch, then S, then cumsum)
  float* out3 = out + 3ull*MR*NC;          // b

  float* wsf = (float*)d_ws;
  float* X  = wsf;                         // MR*NC
  float* H1 = wsf + 1ull*MR*NC;            // MR*NC   (TD early)
  float* H2 = wsf + 2ull*MR*NC;            // MR*NC   (TB early)
  float* DC = wsf + 3ull*MR*NC;            // M3*NC
  float* Pb = DC + (size_t)M3*NC;          // SEG*NC
  float* Pd = Pb + (size_t)SEG*NC;         // SEGD*NC
  float* Pc = Pd + (size_t)SEGD*NC;        // VTILES*NC
  float* TD = H1;                          // M3*NC  (dead before hbox_sq writes H1)
  float* TB = H2;                          // MR*NC  (dead before hbox_sq writes H2)

  seg_sum_both <<<dim3(SEGD+SEG,NC/256),256,0,stream>>>(bneg,dcol,b,w,TD,Pd,TB,Pb);
  scan_excl_both<<<NC/256,256,0,stream>>>(Pd,Pb);
  decay_finalize<<<dim3(SEGD,NC/256),256,0,stream>>>(TD,Pd,DC);
  phase1       <<<dim3(SEG, NC/256),256,0,stream>>>(TB,Pb,DC,fg,fm,bold,hX,recon,out0,out3,X);
  hbox_sq      <<<MR,256,0,stream>>>(X,H1,H2);
  vbox_stage1  <<<dim3(VTILES,NC/256),256,0,stream>>>(H1,H2,out1,out2);
  hbox_two     <<<MR,256,0,stream>>>(out1,out2,H1,H2);
  vbox2_fused  <<<dim3(VTILES,NC/256),256,0,stream>>>(H1,H2,X,ww,out1,out2,Pc);
  scan_excl_t<VTILES><<<NC/256,256,0,stream>>>(Pc);
  phase3_final <<<dim3(VTILES,NC/256),256,0,stream>>>(Pc,out0,out2);
}